// Round 1
// baseline (234.865 us; speedup 1.0000x reference)
//
#include <hip/hip_runtime.h>
#include <hip/hip_bf16.h>

#define DEVI __device__ __forceinline__

typedef __attribute__((ext_vector_type(8))) short short8;
typedef __attribute__((ext_vector_type(8))) unsigned short ushort8;
typedef __attribute__((ext_vector_type(4))) float f32x4;

// problem constants
static constexpr int BB = 32, TT = 64, KIN = 4894, KINP = 4896;
static constexpr int E = 128, HH = 128, NG = 768; // NG = 2 GRUs * 3 gates * 128
static constexpr int NTOK = BB * TT;              // 2048

DEVI unsigned short f2bf(float f) {
    union { float f; unsigned u; } v; v.f = f;
    unsigned r = v.u + 0x7fffu + ((v.u >> 16) & 1u);
    return (unsigned short)(r >> 16);
}
DEVI float sigm(float x) { return __builtin_amdgcn_rcpf(1.f + __expf(-x)); }
DEVI float tanh_(float x) { return 1.f - 2.f * __builtin_amdgcn_rcpf(__expf(2.f * x) + 1.f); }

// ---------------- prep: casts / padding / repacks ----------------
__global__ void prep_kernel(const float* __restrict__ x, const float* __restrict__ Wemb,
                            const float* __restrict__ Wih_a, const float* __restrict__ Wih_b,
                            const float* __restrict__ Whh_a, const float* __restrict__ Whh_b,
                            const float* __restrict__ Wbeta,
                            unsigned short* __restrict__ xbf, unsigned short* __restrict__ wembbf,
                            unsigned short* __restrict__ wihbf, unsigned short* __restrict__ whhbf,
                            unsigned short* __restrict__ wbetabf, float* __restrict__ col128) {
    long job = (long)blockIdx.x * blockDim.x + threadIdx.x;
    const long JX = 2048L * 612, JWE = 128L * 612, JWIH = 768L * 16, JWHH = 768L * 16, JWB = 128L * 16, JCOL = 96;
    if (job < JX) {
        int row = (int)(job / 612), c8 = (int)(job % 612) * 8;
        ushort8 v;
        #pragma unroll
        for (int jj = 0; jj < 8; ++jj) { int c = c8 + jj; v[jj] = (c < KIN) ? f2bf(x[(long)row * KIN + c]) : (unsigned short)0; }
        *(ushort8*)(xbf + (long)row * KINP + c8) = v;
        return;
    }
    job -= JX;
    if (job < JWE) {
        int row = (int)(job / 612), c8 = (int)(job % 612) * 8;
        ushort8 v;
        #pragma unroll
        for (int jj = 0; jj < 8; ++jj) { int c = c8 + jj; v[jj] = (c < KIN) ? f2bf(Wemb[(long)row * KIN + c]) : (unsigned short)0; }
        *(ushort8*)(wembbf + (long)row * KINP + c8) = v;
        return;
    }
    job -= JWE;
    if (job < JWIH) {
        int g = (int)(job / 16), c8 = (int)(job % 16) * 8;
        const float* src = (g < 384) ? (Wih_a + (long)g * 129) : (Wih_b + (long)(g - 384) * 129);
        ushort8 v;
        #pragma unroll
        for (int jj = 0; jj < 8; ++jj) v[jj] = f2bf(src[c8 + jj]);
        *(ushort8*)(wihbf + (long)g * 128 + c8) = v;
        return;
    }
    job -= JWIH;
    if (job < JWHH) {
        int g = (int)(job / 16), c8 = (int)(job % 16) * 8;
        const float* src = (g < 384) ? (Whh_a + (long)g * 128) : (Whh_b + (long)(g - 384) * 128);
        ushort8 v;
        #pragma unroll
        for (int jj = 0; jj < 8; ++jj) v[jj] = f2bf(src[c8 + jj]);
        *(ushort8*)(whhbf + (long)g * 128 + c8) = v;
        return;
    }
    job -= JWHH;
    if (job < JWB) {
        int e = (int)(job / 16), c8 = (int)(job % 16) * 8;
        ushort8 v;
        #pragma unroll
        for (int jj = 0; jj < 8; ++jj) v[jj] = f2bf(Wbeta[(long)e * 128 + c8 + jj]);
        *(ushort8*)(wbetabf + (long)e * 128 + c8) = v;
        return;
    }
    job -= JWB;
    if (job < JCOL) {
        int g0 = (int)job * 8;
        #pragma unroll
        for (int jj = 0; jj < 8; ++jj) {
            int g = g0 + jj;
            col128[g] = (g < 384) ? Wih_a[(long)g * 129 + 128] : Wih_b[(long)(g - 384) * 129 + 128];
        }
    }
}

// ---------------- emb = x @ Wemb^T  (bf16 MFMA, K=4896 padded) ----------------
__global__ __launch_bounds__(256) void emb_gemm(const unsigned short* __restrict__ xbf,
                                                const unsigned short* __restrict__ wembbf,
                                                float* __restrict__ emb, unsigned short* __restrict__ embbf) {
    const int m0 = blockIdx.x * 16;
    const int w = threadIdx.x >> 6, l = threadIdx.x & 63, lr = l & 15, lo = l >> 4;
    const int n0 = (2 * w) * 16 + lr, n1 = (2 * w + 1) * 16 + lr;
    f32x4 acc0 = {0, 0, 0, 0}, acc1 = {0, 0, 0, 0};
    for (int kt = 0; kt < 153; ++kt) {
        int k = kt * 32 + lo * 8;
        short8 a  = *(const short8*)(xbf + (long)(m0 + lr) * KINP + k);
        short8 b0 = *(const short8*)(wembbf + (long)n0 * KINP + k);
        short8 b1 = *(const short8*)(wembbf + (long)n1 * KINP + k);
        acc0 = __builtin_amdgcn_mfma_f32_16x16x32_bf16(a, b0, acc0, 0, 0, 0);
        acc1 = __builtin_amdgcn_mfma_f32_16x16x32_bf16(a, b1, acc1, 0, 0, 0);
    }
    #pragma unroll
    for (int r = 0; r < 4; ++r) {
        int m = m0 + lo * 4 + r;
        emb[(long)m * E + n0] = acc0[r];
        emb[(long)m * E + n1] = acc1[r];
        embbf[(long)m * E + n0] = f2bf(acc0[r]);
        embbf[(long)m * E + n1] = f2bf(acc1[r]);
    }
}

// ---------------- Gi = temb @ Wih_all^T + bih  (MFMA on K=128, t-feature as f32 epilogue) ----------------
__global__ __launch_bounds__(256) void gi_gemm(const unsigned short* __restrict__ embbf,
                                               const unsigned short* __restrict__ wihbf,
                                               const float* __restrict__ t,
                                               const float* __restrict__ bih_a, const float* __restrict__ bih_b,
                                               const float* __restrict__ col128, float* __restrict__ Gi) {
    const int m0 = blockIdx.x * 32;
    const int w = threadIdx.x >> 6, l = threadIdx.x & 63, lr = l & 15, lo = l >> 4;
    f32x4 acc[2][12];
    #pragma unroll
    for (int mt = 0; mt < 2; ++mt)
        #pragma unroll
        for (int nl = 0; nl < 12; ++nl) acc[mt][nl] = (f32x4){0, 0, 0, 0};
    #pragma unroll
    for (int kt = 0; kt < 4; ++kt) {
        int k = kt * 32 + lo * 8;
        short8 a0 = *(const short8*)(embbf + (long)(m0 + lr) * E + k);
        short8 a1 = *(const short8*)(embbf + (long)(m0 + 16 + lr) * E + k);
        #pragma unroll
        for (int nl = 0; nl < 12; ++nl) {
            int n = (w * 12 + nl) * 16 + lr;
            short8 bf = *(const short8*)(wihbf + (long)n * 128 + k);
            acc[0][nl] = __builtin_amdgcn_mfma_f32_16x16x32_bf16(a0, bf, acc[0][nl], 0, 0, 0);
            acc[1][nl] = __builtin_amdgcn_mfma_f32_16x16x32_bf16(a1, bf, acc[1][nl], 0, 0, 0);
        }
    }
    #pragma unroll
    for (int mt = 0; mt < 2; ++mt)
        #pragma unroll
        for (int nl = 0; nl < 12; ++nl) {
            int n = (w * 12 + nl) * 16 + lr;
            float bias = (n < 384) ? bih_a[n] : bih_b[n - 384];
            float cw = col128[n];
            #pragma unroll
            for (int r = 0; r < 4; ++r) {
                int tok = m0 + mt * 16 + lo * 4 + r;
                Gi[(long)tok * NG + n] = acc[mt][nl][r] + bias + t[tok] * cw;
            }
        }
}

// ---------------- recurrence + online-softmax attention ----------------
// grid: 128 blocks = (i in 0..63) x (q in 0..1); block handles 16 chains (b = q*16+c) at position i.
// 8 waves: waves 0-3 -> GRU a gates, waves 4-7 -> GRU b gates; Whh held in registers as bf16 B-frags.
__global__ __launch_bounds__(512, 2) void retain_rec(
    const unsigned short* __restrict__ whhbf, const unsigned short* __restrict__ wbetabf,
    const float* __restrict__ Gi, const float* __restrict__ emb,
    const float* __restrict__ bhh_a, const float* __restrict__ bhh_b,
    const float* __restrict__ w_alpha, const float* __restrict__ b_alpha,
    const float* __restrict__ b_beta, const float* __restrict__ Wout,
    const float* __restrict__ b_out, const int* __restrict__ lengths,
    float* __restrict__ out) {
    const int tid = threadIdx.x;
    const int w = tid >> 6, l = tid & 63, lr = l & 15, lo = l >> 4;
    const int i = blockIdx.x >> 1, q = blockIdx.x & 1;
    const int gru = w >> 2, ub = (w & 3) * 2;

    __shared__ float Hf[2][16][128];
    __shared__ __align__(16) unsigned short Hbf[2][16][128]; // XOR-swizzled: elem idx k ^ ((c&7)*8)
    __shared__ float accv[16][128];
    __shared__ float bhh_s[768];
    __shared__ float bbeta_s[128], walpha_s[128], wout_s[128];
    __shared__ float m_s[16], l_s[16], fac_s[16], p_s[16];

    for (int idx = tid; idx < 768; idx += 512)
        bhh_s[idx] = (idx < 384) ? bhh_a[idx] : bhh_b[idx - 384];
    if (tid < 128) { bbeta_s[tid] = b_beta[tid]; walpha_s[tid] = w_alpha[tid]; wout_s[tid] = Wout[tid]; }
    if (tid < 16) { m_s[tid] = -1e30f; l_s[tid] = 0.f; fac_s[tid] = 0.f; p_s[tid] = 0.f; }
    for (int idx = tid; idx < 2 * 16 * 128; idx += 512) { (&Hf[0][0][0])[idx] = 0.f; (&Hbf[0][0][0])[idx] = 0; }
    for (int idx = tid; idx < 16 * 128; idx += 512) (&accv[0][0])[idx] = 0.f;

    // persistent B-fragments: Whh rows for this wave's (gru, u-tiles, gates)
    short8 Wf[6][4];
    #pragma unroll
    for (int utl = 0; utl < 2; ++utl)
        #pragma unroll
        for (int gt = 0; gt < 3; ++gt)
            #pragma unroll
            for (int kt = 0; kt < 4; ++kt) {
                int n = gru * 384 + gt * 128 + (ub + utl) * 16 + lr;
                Wf[utl * 3 + gt][kt] = *(const short8*)(whhbf + (long)n * 128 + kt * 32 + lo * 8);
            }
    short8 Bf[4]; // beta weights: this wave's e-tile
    #pragma unroll
    for (int kt = 0; kt < 4; ++kt)
        Bf[kt] = *(const short8*)(wbetabf + (long)(w * 16 + lr) * 128 + kt * 32 + lo * 8);

    const float balpha0 = b_alpha[0];
    __syncthreads();

    for (int k = 0; k <= i; ++k) {
        const int j = i - k;
        // phase 1: gh = H[gru] @ Whh^T via MFMA (A from swizzled bf16 LDS)
        f32x4 gh[6];
        #pragma unroll
        for (int n = 0; n < 6; ++n) gh[n] = (f32x4){0, 0, 0, 0};
        short8 Af[4];
        #pragma unroll
        for (int kt = 0; kt < 4; ++kt) {
            int sw = (kt * 32 + lo * 8) ^ ((lr & 7) * 8);
            Af[kt] = *(const short8*)(&Hbf[gru][lr][sw]);
        }
        #pragma unroll
        for (int kt = 0; kt < 4; ++kt)
            #pragma unroll
            for (int n = 0; n < 6; ++n)
                gh[n] = __builtin_amdgcn_mfma_f32_16x16x32_bf16(Af[kt], Wf[n][kt], gh[n], 0, 0, 0);
        __syncthreads(); // all Hbf reads done before gate writes

        // phase 2: gates + state update (each (gru,c,u) owned by exactly one thread)
        #pragma unroll
        for (int utl = 0; utl < 2; ++utl) {
            const int u = (ub + utl) * 16 + lr;
            const float bhr = bhh_s[gru * 384 + u];
            const float bhz = bhh_s[gru * 384 + 128 + u];
            const float bhn = bhh_s[gru * 384 + 256 + u];
            #pragma unroll
            for (int r = 0; r < 4; ++r) {
                const int c = lo * 4 + r;
                const long tok = (long)((q * 16 + c) * 64 + j);
                const float* gi = Gi + tok * NG + gru * 384;
                float gir = gi[u], giz = gi[u + 128], gin = gi[u + 256];
                float rr = sigm(gir + gh[utl * 3 + 0][r] + bhr);
                float zz = sigm(giz + gh[utl * 3 + 1][r] + bhz);
                float nn = tanh_(gin + rr * (gh[utl * 3 + 2][r] + bhn));
                float hold = Hf[gru][c][u];
                float hnew = (1.f - zz) * nn + zz * hold;
                Hf[gru][c][u] = hnew;
                Hbf[gru][c][u ^ ((c & 7) * 8)] = f2bf(hnew);
            }
        }
        __syncthreads();

        // phase 3: beta pre-activation MFMA (all waves) + score/softmax-state (wave 0)
        f32x4 bacc = (f32x4){0, 0, 0, 0};
        #pragma unroll
        for (int kt = 0; kt < 4; ++kt) {
            int sw = (kt * 32 + lo * 8) ^ ((lr & 7) * 8);
            short8 ab = *(const short8*)(&Hbf[1][lr][sw]);
            bacc = __builtin_amdgcn_mfma_f32_16x16x32_bf16(ab, Bf[kt], bacc, 0, 0, 0);
        }
        if (w == 0) {
            const int c = l >> 2, part = l & 3;
            float s = 0.f;
            #pragma unroll
            for (int uu = 0; uu < 32; ++uu) s += Hf[0][c][part * 32 + uu] * walpha_s[part * 32 + uu];
            s += __shfl_xor(s, 1);
            s += __shfl_xor(s, 2);
            if (part == 0) {
                s += balpha0;
                float mo = m_s[c];
                float mn = fmaxf(mo, s);
                float fac = __expf(mo - mn);
                float p = __expf(s - mn);
                l_s[c] = l_s[c] * fac + p;
                m_s[c] = mn; fac_s[c] = fac; p_s[c] = p;
            }
        }
        __syncthreads();

        // phase 4: online context accumulation (each (c,e) owned by one thread)
        {
            const int e = w * 16 + lr;
            const float bb = bbeta_s[e];
            #pragma unroll
            for (int r = 0; r < 4; ++r) {
                const int c = lo * 4 + r;
                const long tok = (long)((q * 16 + c) * 64 + j);
                float beta = tanh_(bacc[r] + bb);
                float ev = emb[tok * E + e];
                accv[c][e] = accv[c][e] * fac_s[c] + p_s[c] * beta * ev;
            }
        }
        // no barrier needed: next phase-1 only reads Hbf; fac_s next written after 2 barriers
    }

    __syncthreads();
    if (w == 0) {
        const int c = l >> 2, part = l & 3;
        float sum = 0.f;
        #pragma unroll
        for (int uu = 0; uu < 32; ++uu) { int e = part * 32 + uu; sum += accv[c][e] * wout_s[e]; }
        sum += __shfl_xor(sum, 1);
        sum += __shfl_xor(sum, 2);
        if (part == 0) {
            const int b = q * 16 + c;
            float val = sum / l_s[c] + b_out[0];
            if (i >= lengths[b]) val = b_out[0];
            out[b * TT + i] = val;
        }
    }
}

// ---------------- launch ----------------
extern "C" void kernel_launch(void* const* d_in, const int* in_sizes, int n_in,
                              void* d_out, int out_size, void* d_ws, size_t ws_size,
                              hipStream_t stream) {
    (void)in_sizes; (void)n_in; (void)out_size; (void)ws_size;
    const float* x       = (const float*)d_in[0];
    const float* t       = (const float*)d_in[1];
    const int*   len     = (const int*)d_in[2];
    const float* Wemb    = (const float*)d_in[3];
    const float* Wih_a   = (const float*)d_in[4];
    const float* Whh_a   = (const float*)d_in[5];
    const float* bih_a   = (const float*)d_in[6];
    const float* bhh_a   = (const float*)d_in[7];
    const float* Wih_b   = (const float*)d_in[8];
    const float* Whh_b   = (const float*)d_in[9];
    const float* bih_b   = (const float*)d_in[10];
    const float* bhh_b   = (const float*)d_in[11];
    const float* w_alpha = (const float*)d_in[12];
    const float* b_alpha = (const float*)d_in[13];
    const float* W_beta  = (const float*)d_in[14];
    const float* b_beta  = (const float*)d_in[15];
    const float* W_out   = (const float*)d_in[16];
    const float* b_out   = (const float*)d_in[17];

    char* ws = (char*)d_ws;
    float*          emb     = (float*)(ws + 0);                      // 2048*128*4   = 1,048,576
    unsigned short* embbf   = (unsigned short*)(ws + 1048576);       // 2048*128*2   =   524,288
    float*          Gi      = (float*)(ws + 1572864);                // 2048*768*4   = 6,291,456
    unsigned short* xbf     = (unsigned short*)(ws + 7864320);       // 2048*4896*2  = 20,054,016
    unsigned short* wembbf  = (unsigned short*)(ws + 27918336);      // 128*4896*2   = 1,253,376
    unsigned short* wihbf   = (unsigned short*)(ws + 29171712);      // 768*128*2    =   196,608
    unsigned short* whhbf   = (unsigned short*)(ws + 29368320);      // 768*128*2    =   196,608
    unsigned short* wbetabf = (unsigned short*)(ws + 29564928);      // 128*128*2    =    32,768
    float*          col128  = (float*)(ws + 29597696);               // 768*4        =     3,072

    const long jobs = 2048L * 612 + 128L * 612 + 768L * 16 + 768L * 16 + 128L * 16 + 96;
    const int prep_blocks = (int)((jobs + 255) / 256);

    prep_kernel<<<prep_blocks, 256, 0, stream>>>(x, Wemb, Wih_a, Wih_b, Whh_a, Whh_b, W_beta,
                                                 xbf, wembbf, wihbf, whhbf, wbetabf, col128);
    emb_gemm<<<128, 256, 0, stream>>>(xbf, wembbf, emb, embbf);
    gi_gemm<<<64, 256, 0, stream>>>(embbf, wihbf, t, bih_a, bih_b, col128, Gi);
    retain_rec<<<128, 512, 0, stream>>>(whhbf, wbetabf, Gi, emb, bhh_a, bhh_b,
                                        w_alpha, b_alpha, b_beta, W_out, b_out, len, (float*)d_out);
}